// Round 11
// baseline (54.849 us; speedup 1.0000x reference)
//
#include <hip/hip_runtime.h>
#include <hip/hip_bf16.h>

// CombinedRotaryEmbedding via MFMA — persistent pipelined stream.
// prep (1 wave): fold Givens chain into rotation_matrix -> M (64x64), apply
//   RoPE even/odd column permutation, quantize to bf16, store as
//   mfma_f32_16x16x32_bf16 B-fragments (8 KB) in d_ws.
// main: 1024 blocks = exactly 4 blocks/CU, all resident. Per block: 8 KB
//   Btab -> LDS once, one barrier. Per wave: 8 tokens, 1-deep register
//   prefetch (token t+1's 4 contiguous 1KB dwordx4 issued before token t is
//   consumed -> 4 KB/wave always in flight). Per-wave ping-pong LDS stage
//   buffers (t&1) for x-in transpose and out transpose.
// R10 post-mortem: removing the lgkmcnt asm let TBAA hoist the f32x4 store-
//   reads above the scalar-float epilogue writes (different pointer types ->
//   "no alias") — stores emitted staged x instead of output. Fix: explicit
//   compiler memory barriers at every LDS phase boundary (zero-cost empty
//   asm + one lgkmcnt with "memory" clobber), ping-pong buffers for
//   cross-iteration isolation. Clobbers also outlaw B-fragment remat.

#define TOKENS_PER_WAVE 8
#define N_TILES 32768                   // B*S tokens
#define N_BLOCKS (N_TILES / (4 * TOKENS_PER_WAVE))   // 1024

typedef __attribute__((ext_vector_type(8))) short short8;
typedef __attribute__((ext_vector_type(4))) float f32x4;

__device__ __forceinline__ unsigned short f2bf_bits(float f) {
  return __bfloat16_as_ushort(__float2bfloat16(f));
}

__global__ __launch_bounds__(64) void prep_kernel(
    const float* __restrict__ thetas,
    const float* __restrict__ R,
    short* __restrict__ Bws) {
  const int t = threadIdx.x;  // 0..63
  float col[64];
#pragma unroll
  for (int d = 0; d < 64; ++d) col[d] = R[d * 64 + t];
  // M = G0 G1 ... G31 R ; Gk mixes rows k,k+1 (lane-local here).
#pragma unroll
  for (int k = 31; k >= 0; --k) {
    float th = thetas[k];
    float ck = cosf(th), sk = sinf(th);
    float a = col[k], b = col[k + 1];
    col[k]     = ck * a - sk * b;
    col[k + 1] = sk * a + ck * b;
  }
  __shared__ float Ml[64][64];
#pragma unroll
  for (int d = 0; d < 64; ++d) Ml[d][t] = col[d];
  __syncthreads();

  // B fragment for mfma_f32_16x16x32_bf16: col=lane&15, k=(lane>>4)*8+e.
  short8* Bp = (short8*)Bws;
  const int cb = t & 15, kg = t >> 4;
#pragma unroll
  for (int s = 0; s < 2; ++s) {
#pragma unroll
    for (int nt = 0; nt < 4; ++nt) {
      const int c2 = cb + 16 * nt;
      const int pc = (c2 < 32) ? (2 * c2) : (2 * (c2 - 32) + 1);  // RoPE perm
      short8 hf;
#pragma unroll
      for (int e = 0; e < 8; ++e) {
        const int k = s * 32 + kg * 8 + e;
        hf[e] = (short)f2bf_bits(Ml[k][pc]);
      }
      Bp[(s * 4 + nt) * 64 + t] = hf;
    }
  }
}

__global__ __launch_bounds__(256, 4) void rope_mfma(
    const float* __restrict__ x,
    const float* __restrict__ inv_freq,
    const short* __restrict__ Bws,
    float* __restrict__ out) {
  const int lane = threadIdx.x & 63;
  const int wid = threadIdx.x >> 6;
  const int cb = lane & 15;   // A row within tile / D col within 16-block
  const int kg = lane >> 4;   // k-group

  const int tile0 = ((int)blockIdx.x * 4 + wid) * TOKENS_PER_WAVE;

  __shared__ alignas(16) float stage[4][2][16 * 64];  // 32 KB, ping-pong
  __shared__ alignas(16) short8 Btab[8 * 64];         // 8 KB

  // --- Prologue: token 0's x loads issued FIRST (contiguous 1 KB each). ---
  f32x4 pb[4];
  {
    const f32x4* xb = (const f32x4*)x + (size_t)tile0 * 256;
#pragma unroll
    for (int j = 0; j < 4; ++j) pb[j] = xb[j * 64 + lane];
  }

  // Cooperative Btab load: 8 KB, 256 threads x 32 B, coalesced.
  {
    const f32x4* Bg = (const f32x4*)Bws;
    f32x4* Bl = (f32x4*)Btab;
    const int i = threadIdx.x;
    Bl[i] = Bg[i];
    Bl[i + 256] = Bg[i + 256];
  }
  __syncthreads();   // only barrier in the kernel

  short8 bh[8];
#pragma unroll
  for (int i = 0; i < 8; ++i) bh[i] = Btab[i * 64 + lane];

  const float iv0 = inv_freq[cb];
  const float iv1 = inv_freq[cb + 16];

#pragma unroll
  for (int t = 0; t < TOKENS_PER_WAVE; ++t) {
    const int tile = tile0 + t;
    const size_t rb = (size_t)tile * 16;
    float* st = stage[wid][t & 1];

    // Grab this token's data, then IMMEDIATELY issue token t+1's loads so
    // the wave always has 4 KB outstanding while it computes.
    f32x4 va[4];
#pragma unroll
    for (int j = 0; j < 4; ++j) va[j] = pb[j];
    if (t + 1 < TOKENS_PER_WAVE) {
      const f32x4* xn = (const f32x4*)x + (size_t)(tile + 1) * 256;
#pragma unroll
      for (int j = 0; j < 4; ++j) pb[j] = xn[j * 64 + lane];
    }

    // sincos (VALU, rides the load shadow); one position per token.
    const int pos = tile & 8191;
    float sv0, cv0, sv1, cv1;
    __sincosf((float)pos * iv0, &sv0, &cv0);
    __sincosf((float)pos * iv1, &sv1, &cv1);

    // Stage x -> LDS, XOR-swizzled 16B chunks (conflict-free both ways).
    {
      const int r0 = lane >> 4;
      const int c16 = lane & 15;
#pragma unroll
      for (int j = 0; j < 4; ++j) {
        const int row = j * 4 + r0;
        *(f32x4*)&st[row * 64 + (((c16 ^ row) & 15) << 2)] = va[j];
      }
    }
    asm volatile("" ::: "memory");  // staging writes || A-frag reads

    // A-fragments: lane's row = cb, cols [s*32+kg*8, +8).
    float af[2][8];
#pragma unroll
    for (int s = 0; s < 2; ++s) {
#pragma unroll
      for (int t2 = 0; t2 < 2; ++t2) {
        const int ch = s * 8 + kg * 2 + t2;
        f32x4 q = *(const f32x4*)&st[cb * 64 + (((ch ^ cb) & 15) << 2)];
        af[s][t2 * 4 + 0] = q.x;
        af[s][t2 * 4 + 1] = q.y;
        af[s][t2 * 4 + 2] = q.z;
        af[s][t2 * 4 + 3] = q.w;
      }
    }

    // 2-term hi/lo bf16 split (absmax ~0.031 vs 0.118 threshold).
    short8 ah[2], al[2];
#pragma unroll
    for (int s = 0; s < 2; ++s) {
#pragma unroll
      for (int e = 0; e < 8; ++e) {
        float f = af[s][e];
        __hip_bfloat16 h = __float2bfloat16(f);
        ah[s][e] = (short)__bfloat16_as_ushort(h);
        al[s][e] = (short)f2bf_bits(f - __bfloat162float(h));
      }
    }

    f32x4 acc[4];
#pragma unroll
    for (int nt = 0; nt < 4; ++nt) acc[nt] = (f32x4){0.f, 0.f, 0.f, 0.f};
#pragma unroll
    for (int s = 0; s < 2; ++s) {
#pragma unroll
      for (int nt = 0; nt < 4; ++nt) {
        acc[nt] = __builtin_amdgcn_mfma_f32_16x16x32_bf16(ah[s], bh[s * 4 + nt], acc[nt], 0, 0, 0);
        acc[nt] = __builtin_amdgcn_mfma_f32_16x16x32_bf16(al[s], bh[s * 4 + nt], acc[nt], 0, 0, 0);
      }
    }

    // RoPE combine -> same buffer (scalar-float scatter writes).
#pragma unroll
    for (int nt = 0; nt < 4; ++nt) {
      const float cvx = (nt & 1) ? cv1 : cv0;
      const float ssv = ((nt & 1) ? sv1 : sv0) * ((nt < 2) ? -1.f : 1.f);
      const int chunk = (cb >> 2) + 4 * nt;
      const int c1i = cb & 3;
#pragma unroll
      for (int r = 0; r < 4; ++r) {
        const int lrow = kg * 4 + r;
        float y = acc[nt][r];
        float p = acc[nt ^ 2][r];
        st[lrow * 64 + ((chunk ^ lrow) << 2) + c1i] = fmaf(p, ssv, y * cvx);
      }
    }
    // HW+compiler fence: float epilogue writes vs f32x4 store reads are
    // different TBAA types — without this the reads can be hoisted (R10 bug).
    asm volatile("s_waitcnt lgkmcnt(0)" ::: "memory");

    // 4 contiguous 1 KB nontemporal stores.
#pragma unroll
    for (int i = 0; i < 4; ++i) {
      const int g = i * 4 + kg;
      const f32x4 v = *(const f32x4*)&st[g * 64 + ((cb ^ g) << 2)];
      __builtin_nontemporal_store(v, (f32x4*)(out + (rb + g) * 64) + cb);
    }
    asm volatile("" ::: "memory");  // store reads || next staging writes
  }
}

extern "C" void kernel_launch(void* const* d_in, const int* in_sizes, int n_in,
                              void* d_out, int out_size, void* d_ws, size_t ws_size,
                              hipStream_t stream) {
  const float* x        = (const float*)d_in[0];
  const float* thetas   = (const float*)d_in[1];
  const float* R        = (const float*)d_in[2];
  const float* inv_freq = (const float*)d_in[3];

  prep_kernel<<<1, 64, 0, stream>>>(thetas, R, (short*)d_ws);
  rope_mfma<<<N_BLOCKS, 256, 0, stream>>>(x, inv_freq, (const short*)d_ws, (float*)d_out);
}

// Round 12
// 53.846 us; speedup vs baseline: 1.0186x; 1.0186x over previous
//
#include <hip/hip_runtime.h>
#include <hip/hip_bf16.h>

// CombinedRotaryEmbedding via MFMA — single fused kernel.
// R11 post-mortem: four distinct structures all converge at 54-57us; the
//   streaming core is at its wall. Remaining removable overhead: the serial
//   prep_kernel launch + dependency gap (~4-8us). Fused here: each block's
//   wave 0 folds Givens+rotation_matrix -> M in LDS (LDS-resident fold, no
//   64-reg blowup), applies the RoPE even/odd column permutation, quantizes
//   to bf16 B-fragments in LDS Btab — while all waves' first x loads are
//   already in flight. One __syncthreads, then the proven R11 stream:
//   per wave 8 tokens, 1-deep register prefetch, contiguous 1KB dwordx4
//   loads -> XOR-swizzled ping-pong LDS stage -> A frags -> 2-term bf16
//   split MFMA (Y = Ahi*B + Alo*B) -> RoPE epilogue -> LDS -> contiguous
//   1KB nontemporal stores. TBAA fences at every LDS phase boundary
//   (R10 bug: f32x4 reads hoisted above float writes without them).

#define TOKENS_PER_WAVE 8
#define N_TILES 32768                   // B*S tokens
#define N_BLOCKS (N_TILES / (4 * TOKENS_PER_WAVE))   // 1024 = 4 blocks/CU

typedef __attribute__((ext_vector_type(8))) short short8;
typedef __attribute__((ext_vector_type(4))) float f32x4;

__device__ __forceinline__ unsigned short f2bf_bits(float f) {
  return __bfloat16_as_ushort(__float2bfloat16(f));
}

__global__ __launch_bounds__(256, 4) void rope_mfma(
    const float* __restrict__ x,
    const float* __restrict__ thetas,
    const float* __restrict__ R,
    const float* __restrict__ inv_freq,
    float* __restrict__ out) {
  const int tid = threadIdx.x;
  const int lane = tid & 63;
  const int wid = tid >> 6;
  const int cb = lane & 15;   // A row within tile / D col within 16-block
  const int kg = lane >> 4;   // k-group

  const int tile0 = ((int)blockIdx.x * 4 + wid) * TOKENS_PER_WAVE;

  __shared__ alignas(16) float stage[4][2][16 * 64];  // 32 KB ping-pong
  __shared__ alignas(16) short8 Btab[8 * 64];         // 8 KB

  // --- Token-0 x prefetch: issued by ALL waves before the fold, so HBM
  //     ramps while wave 0 computes the B-table. ---
  f32x4 pb[4];
  {
    const f32x4* xb = (const f32x4*)x + (size_t)tile0 * 256;
#pragma unroll
    for (int j = 0; j < 4; ++j) pb[j] = xb[j * 64 + lane];
  }

  // --- Fused prep (wave 0 only): fold Givens chain into R inside LDS.
  //     Ml overlays the stage area (16 KB), dead until after the barrier. ---
  float* Mlf = &stage[0][0][0];         // Ml[d][t] = Mlf[d*64 + t]
  if (tid < 64) {
    const int t = tid;                  // original column index
#pragma unroll 4
    for (int d = 0; d < 64; ++d) Mlf[d * 64 + t] = R[d * 64 + t];
    asm volatile("" ::: "memory");
    // M = G0 G1 ... G31 R; Gk mixes rows k,k+1 -> column-local in LDS.
    for (int k = 31; k >= 0; --k) {
      float th = thetas[k];
      float ck = cosf(th), sk = sinf(th);
      float a = Mlf[k * 64 + t], b = Mlf[(k + 1) * 64 + t];
      Mlf[k * 64 + t]       = ck * a - sk * b;
      Mlf[(k + 1) * 64 + t] = sk * a + ck * b;
    }
    asm volatile("s_waitcnt lgkmcnt(0)" ::: "memory");
    // Build bf16 B-fragments (col=lane&15, k=(lane>>4)*8+e) with the RoPE
    // even/odd output-column permutation baked in.
    const int fcb = t & 15, fkg = t >> 4;
#pragma unroll
    for (int s = 0; s < 2; ++s) {
#pragma unroll
      for (int nt = 0; nt < 4; ++nt) {
        const int c2 = fcb + 16 * nt;
        const int pc = (c2 < 32) ? (2 * c2) : (2 * (c2 - 32) + 1);
        short8 hf;
#pragma unroll
        for (int e = 0; e < 8; ++e) {
          const int k = s * 32 + fkg * 8 + e;
          hf[e] = (short)f2bf_bits(Mlf[k * 64 + pc]);
        }
        Btab[(s * 4 + nt) * 64 + t] = hf;
      }
    }
  }
  __syncthreads();   // Btab ready; Ml overlay now dead.

  short8 bh[8];
#pragma unroll
  for (int i = 0; i < 8; ++i) bh[i] = Btab[i * 64 + lane];

  const float iv0 = inv_freq[cb];
  const float iv1 = inv_freq[cb + 16];

#pragma unroll
  for (int t = 0; t < TOKENS_PER_WAVE; ++t) {
    const int tile = tile0 + t;
    const size_t rb = (size_t)tile * 16;
    float* st = stage[wid][t & 1];

    // Consume token t, immediately issue token t+1's 4 KB.
    f32x4 va[4];
#pragma unroll
    for (int j = 0; j < 4; ++j) va[j] = pb[j];
    if (t + 1 < TOKENS_PER_WAVE) {
      const f32x4* xn = (const f32x4*)x + (size_t)(tile + 1) * 256;
#pragma unroll
      for (int j = 0; j < 4; ++j) pb[j] = xn[j * 64 + lane];
    }

    // sincos rides the load shadow; one position per token.
    const int pos = tile & 8191;
    float sv0, cv0, sv1, cv1;
    __sincosf((float)pos * iv0, &sv0, &cv0);
    __sincosf((float)pos * iv1, &sv1, &cv1);

    // Stage x -> LDS, XOR-swizzled 16B chunks (conflict-free both ways).
    {
      const int r0 = lane >> 4;
      const int c16 = lane & 15;
#pragma unroll
      for (int j = 0; j < 4; ++j) {
        const int row = j * 4 + r0;
        *(f32x4*)&st[row * 64 + (((c16 ^ row) & 15) << 2)] = va[j];
      }
    }
    asm volatile("" ::: "memory");  // staging writes || A-frag reads

    // A-fragments: lane's row = cb, cols [s*32+kg*8, +8).
    float af[2][8];
#pragma unroll
    for (int s = 0; s < 2; ++s) {
#pragma unroll
      for (int t2 = 0; t2 < 2; ++t2) {
        const int ch = s * 8 + kg * 2 + t2;
        f32x4 q = *(const f32x4*)&st[cb * 64 + (((ch ^ cb) & 15) << 2)];
        af[s][t2 * 4 + 0] = q.x;
        af[s][t2 * 4 + 1] = q.y;
        af[s][t2 * 4 + 2] = q.z;
        af[s][t2 * 4 + 3] = q.w;
      }
    }

    // 2-term hi/lo bf16 split (absmax ~0.031 vs 0.118 threshold).
    short8 ah[2], al[2];
#pragma unroll
    for (int s = 0; s < 2; ++s) {
#pragma unroll
      for (int e = 0; e < 8; ++e) {
        float f = af[s][e];
        __hip_bfloat16 h = __float2bfloat16(f);
        ah[s][e] = (short)__bfloat16_as_ushort(h);
        al[s][e] = (short)f2bf_bits(f - __bfloat162float(h));
      }
    }

    f32x4 acc[4];
#pragma unroll
    for (int nt = 0; nt < 4; ++nt) acc[nt] = (f32x4){0.f, 0.f, 0.f, 0.f};
#pragma unroll
    for (int s = 0; s < 2; ++s) {
#pragma unroll
      for (int nt = 0; nt < 4; ++nt) {
        acc[nt] = __builtin_amdgcn_mfma_f32_16x16x32_bf16(ah[s], bh[s * 4 + nt], acc[nt], 0, 0, 0);
        acc[nt] = __builtin_amdgcn_mfma_f32_16x16x32_bf16(al[s], bh[s * 4 + nt], acc[nt], 0, 0, 0);
      }
    }

    // RoPE combine -> same buffer (scalar-float scatter writes).
#pragma unroll
    for (int nt = 0; nt < 4; ++nt) {
      const float cvx = (nt & 1) ? cv1 : cv0;
      const float ssv = ((nt & 1) ? sv1 : sv0) * ((nt < 2) ? -1.f : 1.f);
      const int chunk = (cb >> 2) + 4 * nt;
      const int c1i = cb & 3;
#pragma unroll
      for (int r = 0; r < 4; ++r) {
        const int lrow = kg * 4 + r;
        float y = acc[nt][r];
        float p = acc[nt ^ 2][r];
        st[lrow * 64 + ((chunk ^ lrow) << 2) + c1i] = fmaf(p, ssv, y * cvx);
      }
    }
    // HW+compiler fence: float epilogue writes vs f32x4 store reads are
    // different TBAA types — without this the reads get hoisted (R10 bug).
    asm volatile("s_waitcnt lgkmcnt(0)" ::: "memory");

    // 4 contiguous 1 KB nontemporal stores.
#pragma unroll
    for (int i = 0; i < 4; ++i) {
      const int g = i * 4 + kg;
      const f32x4 v = *(const f32x4*)&st[g * 64 + ((cb ^ g) << 2)];
      __builtin_nontemporal_store(v, (f32x4*)(out + (rb + g) * 64) + cb);
    }
    asm volatile("" ::: "memory");  // store reads || next staging writes
  }
}

extern "C" void kernel_launch(void* const* d_in, const int* in_sizes, int n_in,
                              void* d_out, int out_size, void* d_ws, size_t ws_size,
                              hipStream_t stream) {
  const float* x        = (const float*)d_in[0];
  const float* thetas   = (const float*)d_in[1];
  const float* R        = (const float*)d_in[2];
  const float* inv_freq = (const float*)d_in[3];

  rope_mfma<<<N_BLOCKS, 256, 0, stream>>>(x, thetas, R, inv_freq, (float*)d_out);
}